// Round 11
// baseline (421.915 us; speedup 1.0000x reference)
//
#include <hip/hip_runtime.h>

#define B_ 256
#define E_ 1024
#define H_ 1024
#define F_ 2048
#define L_ 196
#define A_ 512
#define ML (B_ * L_)   // 50176

typedef __attribute__((ext_vector_type(8))) short short8;
typedef __attribute__((ext_vector_type(4))) float f32x4;

__device__ __forceinline__ unsigned short f2bf(float x) {
  unsigned u = __float_as_uint(x);
  unsigned r = (u + 0x7FFFu + ((u >> 16) & 1u)) >> 16;   // RNE
  return (unsigned short)r;
}
__device__ __forceinline__ float fast_tanh(float x) {
  x = fminf(fmaxf(x, -15.f), 15.f);
  float e = __expf(2.f * x);
  return (e - 1.f) / (e + 1.f);
}
__device__ __forceinline__ float sigmoidf_(float x) {
  return 1.f / (1.f + __expf(-x));
}

#define GLOAD_LDS(gptr, lptr) \
  __builtin_amdgcn_global_load_lds( \
      (const __attribute__((address_space(1))) void*)(gptr), \
      (__attribute__((address_space(3))) void*)(lptr), 16, 0, 0)

#define SBAR() asm volatile("s_barrier" ::: "memory")

// ---------------- merged weight + xh casts ----------------
// flat ranges: [0,1048576) Wa ; [1048576,1572864) Wha ; [1572864,18350080) Wg ;
// [18350080,18874368) xt|h -> AgB cols 0..2047.  grid = 18874368/2048 = 9216 blocks.
__global__ void cast_wx_k(const float* __restrict__ Wa, const float* __restrict__ Wha,
                          const float* __restrict__ Wi, const float* __restrict__ Wh,
                          const float* __restrict__ Wz, const float* __restrict__ xt,
                          const float* __restrict__ h,
                          unsigned short* __restrict__ WaB, unsigned short* __restrict__ WhaB,
                          unsigned short* __restrict__ WgB, unsigned short* __restrict__ AgB) {
  size_t i = ((size_t)blockIdx.x * 256 + threadIdx.x) * 8;
  const float* src;
  unsigned short* dst;
  if (i < 1048576) { src = Wa + i; dst = WaB + i; }
  else if (i < 1572864) { src = Wha + (i - 1048576); dst = WhaB + (i - 1048576); }
  else if (i < 18350080) {
    size_t off = i - 1572864;
    int row = (int)(off >> 12), col = (int)(off & 4095);
    if (col < 1024)       src = Wi + (size_t)row * 1024 + col;
    else if (col < 2048)  src = Wh + (size_t)row * 1024 + (col - 1024);
    else                  src = Wz + (size_t)row * 2048 + (col - 2048);
    dst = WgB + off;
  } else {
    size_t off = i - 18350080;
    int row = (int)(off >> 11), col = (int)(off & 2047);
    src = (col < 1024) ? (xt + (size_t)row * 1024 + col) : (h + (size_t)row * 1024 + (col - 1024));
    dst = AgB + (size_t)row * 4096 + col;
  }
  float4 a = *reinterpret_cast<const float4*>(src);
  float4 b = *reinterpret_cast<const float4*>(src + 4);
  short8 o;
  o[0] = (short)f2bf(a.x); o[1] = (short)f2bf(a.y); o[2] = (short)f2bf(a.z); o[3] = (short)f2bf(a.w);
  o[4] = (short)f2bf(b.x); o[5] = (short)f2bf(b.y); o[6] = (short)f2bf(b.z); o[7] = (short)f2bf(b.w);
  *reinterpret_cast<short8*>(dst) = o;
}

// ---------------- hlin = h @ Wha^T + bha via MFMA: M=256,N=512,K=1024 ----------------
__global__ __launch_bounds__(256, 2)
void hlin_gemm_k(const unsigned short* __restrict__ AgB, const unsigned short* __restrict__ WhaB,
                 const float* __restrict__ bha, float* __restrict__ hlin) {
  __shared__ unsigned short As[2][64 * 64];
  __shared__ unsigned short Bs[2][128 * 64];
  const int tid = threadIdx.x;
  const int lane = tid & 63, wid = tid >> 6;
  const int wm = wid >> 1, wn = wid & 1;
  const int m0 = blockIdx.y * 64;
  const int n0 = blockIdx.x * 128;
  const int g16 = lane >> 4, l16 = lane & 15;
  const int l7 = l16 & 7;
  f32x4 acc[2][4] = {};

#define STAGE_HL(BUF, KK)                                                                      \
  {                                                                                            \
    _Pragma("unroll")                                                                          \
    for (int it = 0; it < 2; ++it) {                                                           \
      int idx = it * 256 + tid;                                                                \
      int row = idx >> 3;                                                                      \
      int kc = (idx & 7) ^ (row & 7);                                                          \
      GLOAD_LDS(AgB + (size_t)(m0 + row) * 4096 + 1024 + (KK) + kc * 8, &As[BUF][idx * 8]);    \
    }                                                                                          \
    _Pragma("unroll")                                                                          \
    for (int it = 0; it < 4; ++it) {                                                           \
      int idx = it * 256 + tid;                                                                \
      int row = idx >> 3;                                                                      \
      int kc = (idx & 7) ^ (row & 7);                                                          \
      GLOAD_LDS(WhaB + (size_t)(n0 + row) * 1024 + (KK) + kc * 8, &Bs[BUF][idx * 8]);          \
    }                                                                                          \
  }

  STAGE_HL(0, 0);
  STAGE_HL(1, 64);
  asm volatile("s_waitcnt vmcnt(6)" ::: "memory");
  SBAR();
  int cur = 0;
  for (int k0 = 0; k0 < 1024; k0 += 64) {
    #pragma unroll
    for (int ks = 0; ks < 2; ++ks) {
      const int ko = ((ks * 4 + g16) ^ l7) << 3;
      short8 af[2], bfr[4];
      #pragma unroll
      for (int mi = 0; mi < 2; ++mi)
        af[mi] = *reinterpret_cast<const short8*>(&As[cur][(wm * 32 + mi * 16 + l16) * 64 + ko]);
      #pragma unroll
      for (int ni = 0; ni < 4; ++ni)
        bfr[ni] = *reinterpret_cast<const short8*>(&Bs[cur][(wn * 64 + ni * 16 + l16) * 64 + ko]);
      #pragma unroll
      for (int mi = 0; mi < 2; ++mi)
        #pragma unroll
        for (int ni = 0; ni < 4; ++ni)
          acc[mi][ni] = __builtin_amdgcn_mfma_f32_16x16x32_bf16(af[mi], bfr[ni], acc[mi][ni], 0, 0, 0);
    }
    SBAR();
    if (k0 + 128 < 1024) {
      STAGE_HL(cur, k0 + 128);
      asm volatile("s_waitcnt vmcnt(6)" ::: "memory");
    } else {
      asm volatile("s_waitcnt vmcnt(0)" ::: "memory");
    }
    SBAR();
    cur ^= 1;
  }
#undef STAGE_HL

  #pragma unroll
  for (int ni = 0; ni < 4; ++ni) {
    int col = n0 + wn * 64 + ni * 16 + l16;
    float bv = bha[col];
    #pragma unroll
    for (int mi = 0; mi < 2; ++mi)
      #pragma unroll
      for (int j = 0; j < 4; ++j) {
        int m = m0 + wm * 32 + mi * 16 + g16 * 4 + j;
        hlin[(size_t)m * A_ + col] = acc[mi][ni][j] + bv;
      }
  }
}

// ---------------- fused cast+score GEMM v5: full-N, 2 blocks/CU ----------------
// BM=64, BN=512, BK=64, 8 waves. att read ONCE (no N-split).
// LDS = Bs single-buffer 64KB + As dbuf 16KB = 80KB exactly -> 2 blocks/CU.
// A: reg-staged f32 depth-2 + cvt_pk. B: gld_lds each iter after barrier
// (drain covered by the co-resident block's compute, m114).
__global__ __launch_bounds__(512, 2)
void score_fuse_k(const float* __restrict__ att, const unsigned short* __restrict__ WaB,
                  const float* __restrict__ hlin, const float* __restrict__ ba,
                  const float* __restrict__ Wo, float* __restrict__ scores) {
  __shared__ unsigned short As[2][64 * 64];     // 16 KB
  __shared__ unsigned short Bs[512 * 64];       // 64 KB (single buffer)
  const int tid = threadIdx.x;                  // 0..511
  const int lane = tid & 63, wn = tid >> 6;     // 8 waves
  const int m0 = blockIdx.x * 64;
  const int g16 = lane >> 4, l16 = lane & 15;
  const int l7 = l16 & 7;
  f32x4 acc[4][4] = {};
  float4 R[2];

#define LOADA(KK)                                                                        \
  {                                                                                      \
    _Pragma("unroll")                                                                    \
    for (int it = 0; it < 2; ++it) {                                                     \
      int idx = it * 512 + tid;                                                          \
      int row = idx >> 4, kf = idx & 15;                                                 \
      R[it] = *reinterpret_cast<const float4*>(att + (size_t)(m0 + row) * F_ + (KK) + kf * 4); \
    }                                                                                    \
  }
#define GLDB(KK)                                                                         \
  {                                                                                      \
    _Pragma("unroll")                                                                    \
    for (int it = 0; it < 8; ++it) {                                                     \
      int idx = it * 512 + tid;                                                          \
      int row = idx >> 3;                                                                \
      int kc = (idx & 7) ^ (row & 7);                                                    \
      GLOAD_LDS(WaB + (size_t)row * F_ + (KK) + kc * 8, &Bs[idx * 8]);                   \
    }                                                                                    \
  }
#define WRITEA(BUF)                                                                      \
  {                                                                                      \
    _Pragma("unroll")                                                                    \
    for (int it = 0; it < 2; ++it) {                                                     \
      int idx = it * 512 + tid;                                                          \
      int row = idx >> 4, kf = idx & 15;                                                 \
      float4 v = R[it];                                                                  \
      unsigned lo, hi;                                                                   \
      asm("v_cvt_pk_bf16_f32 %0, %1, %2" : "=v"(lo) : "v"(v.x), "v"(v.y));               \
      asm("v_cvt_pk_bf16_f32 %0, %1, %2" : "=v"(hi) : "v"(v.z), "v"(v.w));               \
      uint2 q; q.x = lo; q.y = hi;                                                       \
      int el = row * 64 + (((kf >> 1) ^ (row & 7)) << 3) + ((kf & 1) << 2);              \
      *reinterpret_cast<uint2*>(&As[BUF][el]) = q;                                       \
    }                                                                                    \
  }
#define COMPUTE(BUF)                                                                     \
  {                                                                                      \
    _Pragma("unroll")                                                                    \
    for (int ks = 0; ks < 2; ++ks) {                                                     \
      const int ko = ((ks * 4 + g16) ^ l7) << 3;                                         \
      short8 af[4], bfr[4];                                                              \
      _Pragma("unroll")                                                                  \
      for (int mi = 0; mi < 4; ++mi)                                                     \
        af[mi] = *reinterpret_cast<const short8*>(&As[BUF][(mi * 16 + l16) * 64 + ko]);  \
      _Pragma("unroll")                                                                  \
      for (int ni = 0; ni < 4; ++ni)                                                     \
        bfr[ni] = *reinterpret_cast<const short8*>(&Bs[(wn * 64 + ni * 16 + l16) * 64 + ko]); \
      _Pragma("unroll")                                                                  \
      for (int mi = 0; mi < 4; ++mi)                                                     \
        _Pragma("unroll")                                                                \
        for (int ni = 0; ni < 4; ++ni)                                                   \
          acc[mi][ni] = __builtin_amdgcn_mfma_f32_16x16x32_bf16(af[mi], bfr[ni], acc[mi][ni], 0, 0, 0); \
    }                                                                                    \
  }

  // prologue: A(0) -> As[0]; B(0) staged; A(1) in flight
  LOADA(0);
  GLDB(0);
  asm volatile("s_waitcnt vmcnt(8)" ::: "memory");   // A(0)'s 2 retired; B(0) in flight
  WRITEA(0);
  LOADA(64);                                          // A(1) in flight
  asm volatile("s_waitcnt vmcnt(2)" ::: "memory");   // B(0) done; A(1) still flying
  asm volatile("s_waitcnt lgkmcnt(0)" ::: "memory");
  SBAR();

  for (int t = 0; t < 32; ++t) {
    COMPUTE(t & 1);
    SBAR();                                           // everyone done reading Bs + As[t&1]
    if (t + 1 < 32) {
      GLDB((t + 1) * 64);                             // refill Bs
      asm volatile("s_waitcnt vmcnt(8)" ::: "memory"); // A(t+1)'s 2 (oldest) retired
      WRITEA((t + 1) & 1);
      if (t + 2 < 32) {
        LOADA((t + 2) * 64);                          // A(t+2) in flight across next compute
        asm volatile("s_waitcnt vmcnt(2)" ::: "memory"); // B(t+1) done; A(t+2) flying
      } else {
        asm volatile("s_waitcnt vmcnt(0)" ::: "memory");
      }
      asm volatile("s_waitcnt lgkmcnt(0)" ::: "memory");
      SBAR();
    }
  }
#undef LOADA
#undef GLDB
#undef WRITEA
#undef COMPUTE

  // epilogue: per-wave tanh+Wo partial over its 64 cols, cross-wave reduce in LDS
  // (red overlays As -- free after the loop's final barrier)
  float* red = (float*)&As[0][0];                     // 8*64 floats = 2 KB
  float wo_v[4], ba_v[4];
  int a_v[4];
  #pragma unroll
  for (int ni = 0; ni < 4; ++ni) {
    int a = wn * 64 + ni * 16 + l16;
    a_v[ni] = a; wo_v[ni] = Wo[a]; ba_v[ni] = ba[a];
  }
  #pragma unroll
  for (int mi = 0; mi < 4; ++mi) {
    float rs[4];
    #pragma unroll
    for (int j = 0; j < 4; ++j) {
      int m = m0 + mi * 16 + g16 * 4 + j;
      int b = m / L_;
      const float* hb = hlin + (size_t)b * A_;
      float s = 0.f;
      #pragma unroll
      for (int ni = 0; ni < 4; ++ni) {
        float v = acc[mi][ni][j] + ba_v[ni] + hb[a_v[ni]];
        s += fast_tanh(v) * wo_v[ni];
      }
      rs[j] = s;
    }
    #pragma unroll
    for (int off = 1; off < 16; off <<= 1) {
      #pragma unroll
      for (int j = 0; j < 4; ++j) rs[j] += __shfl_xor(rs[j], off);
    }
    if (l16 == 0) {
      #pragma unroll
      for (int j = 0; j < 4; ++j)
        red[wn * 64 + mi * 16 + g16 * 4 + j] = rs[j];
    }
  }
  __syncthreads();
  if (tid < 64) {
    float s = 0.f;
    #pragma unroll
    for (int w = 0; w < 8; ++w) s += red[w * 64 + tid];
    scores[m0 + tid] = s;
  }
}

// ---------------- fused softmax + z (f32 att) ----------------
__global__ __launch_bounds__(256)
void z_sm_f32_k(const float* __restrict__ att, const float* __restrict__ scores,
                unsigned short* __restrict__ AgB) {
  __shared__ float sm[L_];
  const int b = blockIdx.y;
  const int tid = threadIdx.x;
  if (tid < L_) sm[tid] = scores[b * L_ + tid];
  __syncthreads();
  float mx = -1e30f;
  for (int l = 0; l < L_; ++l) mx = fmaxf(mx, sm[l]);
  float s = 0.f;
  for (int l = 0; l < L_; ++l) s += __expf(sm[l] - mx);
  const float inv = 1.f / s;
  __syncthreads();
  if (tid < L_) sm[tid] = __expf(sm[tid] - mx) * inv;
  __syncthreads();
  const int f0 = blockIdx.x * 1024 + tid * 4;
  const float* base = att + (size_t)b * L_ * F_ + f0;
  float a0 = 0.f, a1 = 0.f, a2 = 0.f, a3 = 0.f;
  #pragma unroll 4
  for (int l = 0; l < L_; ++l) {
    float wl = sm[l];
    float4 a = *reinterpret_cast<const float4*>(base + (size_t)l * F_);
    a0 += wl * a.x; a1 += wl * a.y; a2 += wl * a.z; a3 += wl * a.w;
  }
  ushort4 o;
  o.x = f2bf(a0); o.y = f2bf(a1); o.z = f2bf(a2); o.w = f2bf(a3);
  *reinterpret_cast<ushort4*>(AgB + (size_t)b * 4096 + 2048 + f0) = o;
}

// ---------------- gates GEMM: M=256,N=4096,K=4096. BM=64,BN=64, grid(64,4) ----------------
__global__ __launch_bounds__(256, 4)
void gates_gemm_k(const unsigned short* __restrict__ AgB, const unsigned short* __restrict__ WgB,
                  const float* __restrict__ bi, const float* __restrict__ bh,
                  const float* __restrict__ bz, float* __restrict__ sums) {
  __shared__ unsigned short As[2][64 * 64];
  __shared__ unsigned short Bs[2][64 * 64];
  const int tid = threadIdx.x;
  const int lane = tid & 63, wid = tid >> 6;
  const int wm = wid >> 1, wn = wid & 1;
  const int m0 = blockIdx.y * 64;
  const int n0 = blockIdx.x * 64;
  const int g16 = lane >> 4, l16 = lane & 15;
  const int l7 = l16 & 7;
  f32x4 acc[2][2] = {};

#define STAGE_GG(BUF, KK)                                                               \
  {                                                                                     \
    _Pragma("unroll")                                                                   \
    for (int it = 0; it < 2; ++it) {                                                    \
      int idx = it * 256 + tid;                                                         \
      int row = idx >> 3;                                                               \
      int kc = (idx & 7) ^ (row & 7);                                                   \
      GLOAD_LDS(AgB + (size_t)(m0 + row) * 4096 + (KK) + kc * 8, &As[BUF][idx * 8]);    \
      GLOAD_LDS(WgB + (size_t)(n0 + row) * 4096 + (KK) + kc * 8, &Bs[BUF][idx * 8]);    \
    }                                                                                   \
  }

  STAGE_GG(0, 0);
  STAGE_GG(1, 64);
  asm volatile("s_waitcnt vmcnt(4)" ::: "memory");
  SBAR();
  int cur = 0;
  for (int k0 = 0; k0 < 4096; k0 += 64) {
    #pragma unroll
    for (int ks = 0; ks < 2; ++ks) {
      const int ko = ((ks * 4 + g16) ^ l7) << 3;
      short8 af[2], bfr[2];
      #pragma unroll
      for (int mi = 0; mi < 2; ++mi)
        af[mi] = *reinterpret_cast<const short8*>(&As[cur][(wm * 32 + mi * 16 + l16) * 64 + ko]);
      #pragma unroll
      for (int ni = 0; ni < 2; ++ni)
        bfr[ni] = *reinterpret_cast<const short8*>(&Bs[cur][(wn * 32 + ni * 16 + l16) * 64 + ko]);
      #pragma unroll
      for (int mi = 0; mi < 2; ++mi)
        #pragma unroll
        for (int ni = 0; ni < 2; ++ni)
          acc[mi][ni] = __builtin_amdgcn_mfma_f32_16x16x32_bf16(af[mi], bfr[ni], acc[mi][ni], 0, 0, 0);
    }
    SBAR();
    if (k0 + 128 < 4096) {
      STAGE_GG(cur, k0 + 128);
      asm volatile("s_waitcnt vmcnt(4)" ::: "memory");
    } else {
      asm volatile("s_waitcnt vmcnt(0)" ::: "memory");
    }
    SBAR();
    cur ^= 1;
  }
#undef STAGE_GG

  #pragma unroll
  for (int ni = 0; ni < 2; ++ni) {
    int col = n0 + wn * 32 + ni * 16 + l16;
    float bsum = bi[col] + bh[col] + bz[col];
    #pragma unroll
    for (int mi = 0; mi < 2; ++mi)
      #pragma unroll
      for (int j = 0; j < 4; ++j) {
        int m = m0 + wm * 32 + mi * 16 + g16 * 4 + j;
        sums[(size_t)m * 4096 + col] = acc[mi][ni][j] + bsum;
      }
  }
}

// ---------------- gates + zoneout elementwise ----------------
__global__ void final_k(const float* __restrict__ sums, const float* __restrict__ h,
                        const float* __restrict__ c, float* __restrict__ out) {
  int i = blockIdx.x * 256 + threadIdx.x;   // 0 .. B_*H_-1
  int b = i >> 10, hh = i & 1023;
  const float* srow = sums + (size_t)b * 4096;
  float ig = sigmoidf_(srow[hh]);
  float fg = sigmoidf_(srow[1024 + hh]);
  float og = sigmoidf_(srow[2048 + hh]);
  float g  = fast_tanh(srow[3072 + hh]);
  float cv = c[i], hv = h[i];
  float nc = 0.5f * cv + 0.5f * (fg * cv + ig * g);
  float nh = 0.5f * hv + 0.5f * (og * fast_tanh(nc));
  out[i] = nh;
  out[B_ * H_ + i] = nh;
  out[2 * B_ * H_ + i] = nc;
}

extern "C" void kernel_launch(void* const* d_in, const int* in_sizes, int n_in,
                              void* d_out, int out_size, void* d_ws, size_t ws_size,
                              hipStream_t stream) {
  const float* xt  = (const float*)d_in[0];
  const float* att = (const float*)d_in[1];
  const float* h   = (const float*)d_in[2];
  const float* c   = (const float*)d_in[3];
  const float* Wi  = (const float*)d_in[4];
  const float* bi  = (const float*)d_in[5];
  const float* Wh  = (const float*)d_in[6];
  const float* bh  = (const float*)d_in[7];
  const float* Wz  = (const float*)d_in[8];
  const float* bz  = (const float*)d_in[9];
  const float* Wa  = (const float*)d_in[10];
  const float* ba  = (const float*)d_in[11];
  const float* Wha = (const float*)d_in[12];
  const float* bha = (const float*)d_in[13];
  const float* Wo  = (const float*)d_in[14];
  // bo (d_in[15]) is a constant shift under softmax -> dropped.

  char* ws = (char*)d_ws;
  const size_t MB = (size_t)1 << 20;
  unsigned short* WaB  = (unsigned short*)(ws);                // 2 MB
  unsigned short* WhaB = (unsigned short*)(ws + 2 * MB);       // 1 MB
  unsigned short* WgB  = (unsigned short*)(ws + 3 * MB);       // 32 MB
  unsigned short* AgB  = (unsigned short*)(ws + 35 * MB);      // 2 MB
  float* hlin    = (float*)(ws + 37 * MB);                     // 0.5 MB
  float* scores  = (float*)(ws + 38 * MB);                     // 0.2 MB
  float* sums    = (float*)(ws + 40 * MB);                     // 4 MB
  float* out = (float*)d_out;

  cast_wx_k<<<9216, 256, 0, stream>>>(Wa, Wha, Wi, Wh, Wz, xt, h, WaB, WhaB, WgB, AgB);
  hlin_gemm_k<<<dim3(4, 4), 256, 0, stream>>>(AgB, WhaB, bha, hlin);
  score_fuse_k<<<ML / 64, 512, 0, stream>>>(att, WaB, hlin, ba, Wo, scores);
  z_sm_f32_k<<<dim3(2, B_), 256, 0, stream>>>(att, scores, AgB);
  gates_gemm_k<<<dim3(64, 4), 256, 0, stream>>>(AgB, WgB, bi, bh, bz, sums);
  final_k<<<B_ * H_ / 256, 256, 0, stream>>>(sums, h, c, out);
}